// Round 5
// baseline (68.806 us; speedup 1.0000x reference)
//
#include <hip/hip_runtime.h>
#include <stdint.h>

#define B_ROWS 128
#define V_COLS 128000
#define BPR 16                       // blocks per row
#define SLICE (V_COLS / BPR)         // 8000 floats
#define N4 (SLICE / 4)               // 2000 float4
#define NTHR 256
#define CAP 2048

// pair compare, descending order, ties: larger idx first
// (reversed view == reference's stable ascending argsort)
__device__ __forceinline__ bool pgt(float af, uint32_t ai, float bf, uint32_t bi) {
    return (af > bf) || (af == bf && ai > bi);
}

// ---- merge two descending sorted 64-runs (1 elem/lane): keep top-64, sorted desc ----
__device__ __forceinline__ void merge64(float& af, uint32_t& ai,
                                        float bf, uint32_t bi, int lane) {
    float    of = __shfl_xor(bf, 63, 64);
    uint32_t oi = (uint32_t)__shfl_xor((int)bi, 63, 64);
    if (!pgt(af, ai, of, oi)) { af = of; ai = oi; }
    #pragma unroll
    for (int j = 32; j >= 1; j >>= 1) {
        float    cf = __shfl_xor(af, j, 64);
        uint32_t ci = (uint32_t)__shfl_xor((int)ai, j, 64);
        bool sg = pgt(af, ai, cf, ci);
        bool keep = ((lane & j) == 0) ? sg : !sg;
        if (!keep) { af = cf; ai = ci; }
    }
}

// ---- in-register wave bitonic sort of 64 (f,idx) pairs, descending ----
__device__ __forceinline__ void wave_sort64(float& f, uint32_t& i, int lane) {
    #pragma unroll
    for (int ksz = 2; ksz <= 64; ksz <<= 1) {
        #pragma unroll
        for (int j = ksz >> 1; j > 0; j >>= 1) {
            float    of = __shfl_xor(f, j, 64);
            uint32_t oi = (uint32_t)__shfl_xor((int)i, j, 64);
            bool asc   = (lane & ksz) == 0;
            bool lower = (lane & j) == 0;
            bool sg = pgt(f, i, of, oi);
            bool keep = (asc == lower) ? sg : !sg;
            if (!keep) { f = of; i = oi; }
        }
    }
}

// ---- LDS bitonic (fallback only), descending, ties: larger idx first ----
__device__ __forceinline__ void lds_bitonic_desc(float* sf, uint32_t* si, int NP) {
    const int tid = threadIdx.x;
    for (int ksz = 2; ksz <= NP; ksz <<= 1) {
        for (int j = ksz >> 1; j > 0; j >>= 1) {
            __syncthreads();
            for (int i = tid; i < NP; i += NTHR) {
                int ixj = i ^ j;
                if (ixj > i) {
                    float fa = sf[i], fb = sf[ixj];
                    uint32_t ia = si[i], ib = si[ixj];
                    bool a_lt = pgt(fb, ib, fa, ia);  // a strictly after b in desc order
                    if (((i & ksz) == 0) ? a_lt : !a_lt) {
                        sf[i] = fb; sf[ixj] = fa;
                        si[i] = ib; si[ixj] = ia;
                    }
                }
            }
        }
    }
    __syncthreads();
}

__global__ __launch_bounds__(NTHR, 8) void fused_topk_sample_kernel(
    const float* __restrict__ logits, const int* __restrict__ kk,
    const float* __restrict__ pp, const float* __restrict__ noise,
    float* __restrict__ ws_f, uint32_t* __restrict__ ws_i,
    unsigned int* __restrict__ counters, int* __restrict__ out)
{
    __shared__ float    s_f[CAP];
    __shared__ uint32_t s_i[CAP];
    __shared__ float    s_T[4];
    __shared__ int s_cnt;
    __shared__ int s_last;

    const int blk = blockIdx.x;
    const int row = blk >> 4;
    const int q   = blk & 15;
    const int tid = threadIdx.x;
    const int lane = tid & 63;
    const int wv   = tid >> 6;

    if (tid == 0) s_cnt = 0;

    const float4* src = (const float4*)(logits + (size_t)row * V_COLS + (size_t)q * SLICE);

    // ---- 8 independent dwordx4 loads in flight (branch-free clamp) ----
    float4 g[8];
    #pragma unroll
    for (int j = 0; j < 8; ++j) {
        int i4 = j * NTHR + tid;
        i4 = (i4 < N4) ? i4 : (N4 - 1);      // only j==7 can clamp
        g[j] = src[i4];
    }
    if (7 * NTHR + tid >= N4) {
        g[7].x = -INFINITY; g[7].y = -INFINITY; g[7].z = -INFINITY; g[7].w = -INFINITY;
    }

    // ---- per-thread max (float domain; fmaxf trees fuse to v_max3) ----
    float mx = -INFINITY;
    #pragma unroll
    for (int j = 0; j < 8; ++j)
        mx = fmaxf(mx, fmaxf(fmaxf(g[j].x, g[j].y), fmaxf(g[j].z, g[j].w)));

    // ---- per-wave ascending register sort of the 64 thread-maxes ----
    float v = mx;
    #pragma unroll
    for (int ksz = 2; ksz <= 64; ksz <<= 1) {
        #pragma unroll
        for (int j = ksz >> 1; j > 0; j >>= 1) {
            float o = __shfl_xor(v, j, 64);
            bool asc   = (lane & ksz) == 0;
            bool lower = (lane & j) == 0;
            float mn = fminf(v, o), mh = fmaxf(v, o);
            v = (asc == lower) ? mn : mh;
        }
    }
    // lane 48 = 16th-largest thread-max of this wave -> >=16 slice elems >= Tw
    float Tw = __shfl(v, 48, 64);
    if (lane == 0) s_T[wv] = Tw;
    __syncthreads();
    float T = fminf(fminf(s_T[0], s_T[1]), fminf(s_T[2], s_T[3]));  // >=64 elems >= T

    // ---- append candidates (expected ~100-250 per block) ----
    #pragma unroll
    for (int j = 0; j < 8; ++j) {
        const int base = q * SLICE + (j * NTHR + tid) * 4;
        if (g[j].x >= T) { int p = atomicAdd(&s_cnt, 1); if (p < CAP) { s_f[p] = g[j].x; s_i[p] = (uint32_t)(base + 0); } }
        if (g[j].y >= T) { int p = atomicAdd(&s_cnt, 1); if (p < CAP) { s_f[p] = g[j].y; s_i[p] = (uint32_t)(base + 1); } }
        if (g[j].z >= T) { int p = atomicAdd(&s_cnt, 1); if (p < CAP) { s_f[p] = g[j].z; s_i[p] = (uint32_t)(base + 2); } }
        if (g[j].w >= T) { int p = atomicAdd(&s_cnt, 1); if (p < CAP) { s_f[p] = g[j].w; s_i[p] = (uint32_t)(base + 3); } }
    }
    __syncthreads();
    int cnt = s_cnt; if (cnt > CAP) cnt = CAP;

    if (cnt <= 256) {
        // fast path: pad to 256, per-wave register sort, wave-0 tournament merge
        for (int i = cnt + tid; i < 256; i += NTHR) { s_f[i] = -INFINITY; s_i[i] = 0xFFFFFFFFu; }
        __syncthreads();
        float    cf = s_f[wv * 64 + lane];
        uint32_t ci = s_i[wv * 64 + lane];
        wave_sort64(cf, ci, lane);
        s_f[wv * 64 + lane] = cf;
        s_i[wv * 64 + lane] = ci;
        __syncthreads();
        if (wv == 0) {
            float b1f = s_f[64 + lane];  uint32_t b1i = s_i[64 + lane];
            float b2f = s_f[128 + lane]; uint32_t b2i = s_i[128 + lane];
            float b3f = s_f[192 + lane]; uint32_t b3i = s_i[192 + lane];
            merge64(cf, ci, b1f, b1i, lane);
            merge64(b2f, b2i, b3f, b3i, lane);
            merge64(cf, ci, b2f, b2i, lane);
            ws_f[blk * 64 + lane] = cf;
            ws_i[blk * 64 + lane] = ci;
        }
    } else {
        // fallback (pathological data only)
        int NP = 256; while (NP < cnt) NP <<= 1;
        for (int i = cnt + tid; i < NP; i += NTHR) { s_f[i] = -INFINITY; s_i[i] = 0xFFFFFFFFu; }
        lds_bitonic_desc(s_f, s_i, NP);
        if (tid < 64) { ws_f[blk * 64 + tid] = s_f[tid]; ws_i[blk * 64 + tid] = s_i[tid]; }
    }
    __syncthreads();   // drains vmcnt: all ws stores of this block complete

    // ---- last-block-of-row detection (poison-tolerant, self-resetting) ----
    if (tid == 0) {
        __threadfence();                                   // release our ws writes (agent scope)
        unsigned int raw = atomicAdd(&counters[row], 1u);  // device-scope by default
        unsigned int eff = (raw >= 0xAAAAAAAAu) ? (raw - 0xAAAAAAAAu) : raw;
        s_last = (eff == 15u) ? 1 : 0;
        if (s_last) {
            counters[row] = 0u;       // reset for next replay (all adds for this row are done)
            __threadfence();          // acquire: invalidate so we see other XCDs' ws writes
        }
    }
    __syncthreads();
    if (!s_last) return;

    // ================= finalize: merge 16 runs + sample (last block only) =================
    const float*    bf = ws_f + (size_t)row * (BPR * 64);
    const uint32_t* bi = ws_i + (size_t)row * (BPR * 64);

    float    a0f = bf[(wv * 4 + 0) * 64 + lane]; uint32_t a0i = bi[(wv * 4 + 0) * 64 + lane];
    float    a1f = bf[(wv * 4 + 1) * 64 + lane]; uint32_t a1i = bi[(wv * 4 + 1) * 64 + lane];
    float    a2f = bf[(wv * 4 + 2) * 64 + lane]; uint32_t a2i = bi[(wv * 4 + 2) * 64 + lane];
    float    a3f = bf[(wv * 4 + 3) * 64 + lane]; uint32_t a3i = bi[(wv * 4 + 3) * 64 + lane];
    merge64(a0f, a0i, a1f, a1i, lane);
    merge64(a2f, a2i, a3f, a3i, lane);
    merge64(a0f, a0i, a2f, a2i, lane);
    s_f[wv * 64 + lane] = a0f;
    s_i[wv * 64 + lane] = a0i;
    __syncthreads();

    if (wv == 0) {
        float b1f = s_f[64 + lane];  uint32_t b1i = s_i[64 + lane];
        float b2f = s_f[128 + lane]; uint32_t b2i = s_i[128 + lane];
        float b3f = s_f[192 + lane]; uint32_t b3i = s_i[192 + lane];
        merge64(a0f, a0i, b1f, b1i, lane);
        merge64(b2f, b2i, b3f, b3i, lane);
        merge64(a0f, a0i, b2f, b2i, lane);
        // lane j now holds the (j+1)-th largest logit of the row, exact order

        float v2 = a0f;
        uint32_t tok = a0i;
        int k = kk[row];
        if (k > 64) k = 64;                    // safety; setup guarantees k<=63
        float p = pp[row];

        // top-k: threshold = k-th largest; keep v >= thr (value-domain, ties kept)
        float thrv = __shfl(v2, k - 1, 64);
        bool kept = v2 >= thrv;
        float m = __shfl(v2, 0, 64);           // row max
        float e = kept ? expf(v2 - m) : 0.0f;

        // softmax denom over kept
        float denom = e;
        #pragma unroll
        for (int off = 1; off < 64; off <<= 1) denom += __shfl_xor(denom, off, 64);
        float prob = e / denom;

        // ascending-inclusive cumsum == suffix sum over descending lanes
        float cums = prob;
        #pragma unroll
        for (int off = 1; off < 64; off <<= 1) {
            float o = __shfl_down(cums, off, 64);
            cums += (lane + off < 64) ? o : 0.0f;
        }
        // top-p: mask cumsum <= 1-p, but always keep the max (lane 0)
        bool masked = (cums <= 1.0f - p) && (lane != 0);
        bool surv = kept && !masked;

        // renormalize over survivors
        float e2 = surv ? e : 0.0f;
        float denom2 = e2;
        #pragma unroll
        for (int off = 1; off < 64; off <<= 1) denom2 += __shfl_xor(denom2, off, 64);

        float score = -1.0f;
        uint32_t bidx = 0xFFFFFFFFu;
        if (surv) {
            float nz = noise[(size_t)row * V_COLS + tok];
            score = (e / denom2) / nz;         // probs / Exp(1) noise
            bidx = tok;
        }
        // argmax, tie -> smaller token index (matches jnp first-occurrence)
        #pragma unroll
        for (int off = 1; off < 64; off <<= 1) {
            float os = __shfl_xor(score, off, 64);
            uint32_t oi = __shfl_xor(bidx, off, 64);
            if (os > score || (os == score && oi < bidx)) { score = os; bidx = oi; }
        }
        if (lane == 0) out[row] = (int)bidx;
    }
}

extern "C" void kernel_launch(void* const* d_in, const int* in_sizes, int n_in,
                              void* d_out, int out_size, void* d_ws, size_t ws_size,
                              hipStream_t stream) {
    const float* logits = (const float*)d_in[0];
    const int* kk       = (const int*)d_in[1];
    const float* pp     = (const float*)d_in[2];
    const float* noise  = (const float*)d_in[3];
    int* out            = (int*)d_out;

    float*        ws_f = (float*)d_ws;                                  // 2048*64 f32
    uint32_t*     ws_i = (uint32_t*)d_ws + (size_t)B_ROWS * BPR * 64;   // 2048*64 u32
    unsigned int* cnt  = (unsigned int*)d_ws + 2 * (size_t)B_ROWS * BPR * 64; // 128 u32

    fused_topk_sample_kernel<<<B_ROWS * BPR, NTHR, 0, stream>>>(
        logits, kk, pp, noise, ws_f, ws_i, cnt, out);
}